// Round 3
// baseline (898.658 us; speedup 1.0000x reference)
//
#include <hip/hip_runtime.h>
#include <math.h>

#define NN 768
#define CSn 384
#define CZn 128
#define Cn 16
#define Hn 12
#define PQn 4
#define PVn 8
#define CONCATn 2112
#define LGS 772    // logits LDS row stride
#define STG 130    // z stage row stride (floats): b64-aligned, 4-way-conflict max

// ---------------------------------------------------------------------------
// Kernel 1: input projections.  96 blocks x 8 rows each.
//   q      : [N][H*C]
//   kT     : [H*C][N]   (transposed for coalesced row_kernel reads)
//   v      : [N][H][C]
//   q_pts  : [N][H*PQ][3] (global frame)
//   kpT    : [H*PQ*3][N] (transposed, global frame)
//   v_pts  : [N][H][PV][3]
// ---------------------------------------------------------------------------
__global__ __launch_bounds__(256) void proj_kernel(
    const float* __restrict__ s, const float* __restrict__ rot, const float* __restrict__ trans,
    const float* __restrict__ Wq, const float* __restrict__ bq,
    const float* __restrict__ Wkv, const float* __restrict__ bkv,
    const float* __restrict__ Wqp, const float* __restrict__ bqp,
    const float* __restrict__ Wkvp, const float* __restrict__ bkvp,
    float* __restrict__ q, float* __restrict__ kT, float* __restrict__ v,
    float* __restrict__ q_pts, float* __restrict__ kpT, float* __restrict__ v_pts)
{
    const int rt = blockIdx.x;         // 0..95
    const int t  = threadIdx.x;
    const int r0 = rt * 8;
    __shared__ float sl[8][CSn];       // 12 KB
    __shared__ float lin[8][1152];     // 36.9 KB

    const float4* s4 = (const float4*)(s + (size_t)r0 * CSn);
    for (int idx = t; idx < 8 * CSn / 4; idx += 256)
        ((float4*)&sl[0][0])[idx] = s4[idx];
    __syncthreads();

    for (int slot = t; slot < 288; slot += 256) {
        const int col = slot * 4;
        const float* W; const float* bias; int cw; int fout;
        if (col < 192)      { W = Wq;   bias = bq;   cw = col;       fout = 192; }
        else if (col < 576) { W = Wkv;  bias = bkv;  cw = col - 192; fout = 384; }
        else if (col < 720) { W = Wqp;  bias = bqp;  cw = col - 576; fout = 144; }
        else                { W = Wkvp; bias = bkvp; cw = col - 720; fout = 432; }
        float4 bv = *(const float4*)(bias + cw);
        float4 acc[8];
        #pragma unroll
        for (int r = 0; r < 8; ++r) acc[r] = bv;
        const float* Wp = W + cw;
        #pragma unroll 8
        for (int kk = 0; kk < CSn; ++kk) {
            float4 w = *(const float4*)(Wp + (size_t)kk * fout);
            #pragma unroll
            for (int r = 0; r < 8; ++r) {
                float cv = sl[r][kk];
                acc[r].x += cv * w.x; acc[r].y += cv * w.y;
                acc[r].z += cv * w.z; acc[r].w += cv * w.w;
            }
        }
        #pragma unroll
        for (int r = 0; r < 8; ++r) *(float4*)&lin[r][col] = acc[r];
    }
    __syncthreads();

    for (int r = 0; r < 8; ++r) {
        const int i = r0 + r;
        if (t < 192) q[(size_t)i * 192 + t] = lin[r][t];
        // k -> kT (transposed), v -> [i][h][c]
        for (int tt = t; tt < 384; tt += 256) {
            const int h = tt >> 5, cc = tt & 31;
            const float val = lin[r][192 + tt];
            if (cc < 16) kT[(size_t)(h * 16 + cc) * NN + i] = val;
            else         v[((size_t)i * Hn + h) * Cn + (cc - 16)] = val;
        }
        const float R0 = rot[i*9+0], R1 = rot[i*9+1], R2 = rot[i*9+2];
        const float R3 = rot[i*9+3], R4 = rot[i*9+4], R5 = rot[i*9+5];
        const float R6 = rot[i*9+6], R7 = rot[i*9+7], R8 = rot[i*9+8];
        const float T0 = trans[i*3+0], T1 = trans[i*3+1], T2 = trans[i*3+2];
        if (t < 48) {   // q points
            const float px = lin[r][576 + t], py = lin[r][576 + 48 + t], pz = lin[r][576 + 96 + t];
            const float gx = R0*px + R1*py + R2*pz + T0;
            const float gy = R3*px + R4*py + R5*pz + T1;
            const float gz = R6*px + R7*py + R8*pz + T2;
            float* qp = q_pts + ((size_t)i * 48 + t) * 3;
            qp[0] = gx; qp[1] = gy; qp[2] = gz;
        }
        if (t < 144) {  // kv points
            const float px = lin[r][720 + t], py = lin[r][720 + 144 + t], pz = lin[r][720 + 288 + t];
            const float gx = R0*px + R1*py + R2*pz + T0;
            const float gy = R3*px + R4*py + R5*pz + T1;
            const float gz = R6*px + R7*py + R8*pz + T2;
            const int h = t / 12, pp = t % 12;
            if (pp < 4) {
                float* dst = kpT + (size_t)(h * 12 + pp * 3) * NN + i;
                dst[0] = gx; dst[NN] = gy; dst[2*NN] = gz;
            } else {
                float* dst = v_pts + ((size_t)i * Hn + h) * PVn * 3 + (pp - 4) * 3;
                dst[0] = gx; dst[1] = gy; dst[2] = gz;
            }
        }
    }
}

// ---------------------------------------------------------------------------
// Kernel 2: per-row fused IPA.  One block per query row i.
// Phase A: coalesced z staging (64-row tiles, f-mapped float2 loads), each
//          wave owns 3 heads over all 128 channels (Wb/q/qp wave-uniform ->
//          SGPR operands).
// ---------------------------------------------------------------------------
__global__ __launch_bounds__(256) void row_kernel(
    const float* __restrict__ z, const float* __restrict__ mask,
    const float* __restrict__ rot, const float* __restrict__ trans,
    const float* __restrict__ q, const float* __restrict__ kT, const float* __restrict__ v,
    const float* __restrict__ q_pts, const float* __restrict__ kpT, const float* __restrict__ v_pts,
    const float* __restrict__ Wb, const float* __restrict__ bb, const float* __restrict__ head_w,
    float* __restrict__ cat)
{
    const int i = blockIdx.x;
    const int t = threadIdx.x;
    __shared__ float lg[Hn * LGS];             // 37056 B : logits / attention
    __shared__ float uA[64 * STG];             // 33280 B : stage  (phase A)
    float (*part)[Hn * CZn] = (float (*)[Hn * CZn])uA;   // 12288 B (phase C)
    float* ptsum = uA + 2 * Hn * CZn;                    // 1152 B

    const float S_QK = 0.14433756729740643f;   // sqrt(1/48)
    const float S_B  = 0.5773502691896258f;    // sqrt(1/3)
    const float S_PT = 0.1360827634879543f;    // sqrt(1/54)

    const int w = t >> 6, l = t & 63;
    const float mi = mask[i];

    // ---------------- Phase A: logits --------------------------------------
    {
        const float* qrow  = q     + (size_t)i * Hn * Cn;
        const float* qprow = q_pts + (size_t)i * Hn * PQn * 3;
        // hoist q/q_pts/coef for this wave's 3 heads (wave-uniform -> SGPR)
        float qh[3][16], qph[3][12], coefh[3], bb3[3];
        #pragma unroll
        for (int hh = 0; hh < 3; ++hh) {
            const int h = 3 * w + hh;
            #pragma unroll
            for (int c = 0; c < 16; ++c) qh[hh][c] = qrow[h * 16 + c];
            #pragma unroll
            for (int e = 0; e < 12; ++e) qph[hh][e] = qprow[h * 12 + e];
            coefh[hh] = -0.5f * S_PT * log1pf(expf(head_w[h]));
            bb3[hh] = bb[h];
        }

        const float* zi = z + (size_t)i * NN * CZn;
        float2 nxt[16];
        #pragma unroll
        for (int u = 0; u < 16; ++u)
            nxt[u] = *(const float2*)(zi + (size_t)(4 * u + w) * CZn + 2 * l);

        #pragma unroll 1
        for (int tl = 0; tl < 12; ++tl) {
            const int jt0 = tl * 64;
            __syncthreads();                       // stage free
            #pragma unroll
            for (int u = 0; u < 16; ++u)
                *(float2*)(uA + (4 * u + w) * STG + 2 * l) = nxt[u];
            if (tl < 11) {
                const int jn = jt0 + 64;
                #pragma unroll
                for (int u = 0; u < 16; ++u)
                    nxt[u] = *(const float2*)(zi + (size_t)(jn + 4 * u + w) * CZn + 2 * l);
            }
            __syncthreads();                       // stage ready

            const int j = jt0 + l;
            float bh0 = bb3[0], bh1 = bb3[1], bh2 = bb3[2];
            const float* srow = uA + l * STG;
            #pragma unroll 8
            for (int e = 0; e < 64; ++e) {
                float2 zv = *(const float2*)(srow + 2 * e);
                const float* wb = Wb + (2 * e) * Hn + 3 * w;    // wave-uniform -> s_load
                bh0 += zv.x * wb[0] + zv.y * wb[Hn + 0];
                bh1 += zv.x * wb[1] + zv.y * wb[Hn + 1];
                bh2 += zv.x * wb[2] + zv.y * wb[Hn + 2];
            }
            const float mterm = 100000.0f * (mi * mask[j] - 1.0f);
            float bhv[3] = {bh0, bh1, bh2};
            #pragma unroll
            for (int hh = 0; hh < 3; ++hh) {
                const int h = 3 * w + hh;
                float qk = 0.f;
                const float* kc = kT + (size_t)(h * 16) * NN + j;
                #pragma unroll
                for (int c = 0; c < 16; ++c) qk += qh[hh][c] * kc[(size_t)c * NN];
                float d2s = 0.f;
                const float* kp = kpT + (size_t)(h * 12) * NN + j;
                #pragma unroll
                for (int e = 0; e < 12; ++e) { float d = qph[hh][e] - kp[(size_t)e * NN]; d2s += d * d; }
                lg[h * LGS + j] = S_QK * qk + S_B * bhv[hh] + coefh[hh] * d2s + mterm;
            }
        }
    }
    __syncthreads();

    // ---------------- Phase B: softmax over j (wave w owns 3 heads) --------
    {
        for (int hh = 0; hh < 3; ++hh) {
            const int h = w * 3 + hh;
            float e[12];
            #pragma unroll
            for (int u = 0; u < 12; ++u) e[u] = lg[h * LGS + l + u * 64];
            float m = -1e30f;
            #pragma unroll
            for (int u = 0; u < 12; ++u) m = fmaxf(m, e[u]);
            #pragma unroll
            for (int off = 32; off > 0; off >>= 1) m = fmaxf(m, __shfl_xor(m, off));
            float ssum = 0.f;
            #pragma unroll
            for (int u = 0; u < 12; ++u) { e[u] = expf(e[u] - m); ssum += e[u]; }
            #pragma unroll
            for (int off = 32; off > 0; off >>= 1) ssum += __shfl_xor(ssum, off);
            const float inv = 1.0f / ssum;
            #pragma unroll
            for (int u = 0; u < 12; ++u) lg[h * LGS + l + u * 64] = e[u] * inv;
        }
    }
    __syncthreads();

    // ---------------- Phase C: o_pair = a . z  (z row from L3/L2) ----------
    {
        const int half = t >> 7, tt = t & 127;
        const int hset = tt >> 5, c4 = tt & 31;
        const float* zb = z + (size_t)i * NN * CZn + c4 * 4;
        float acc[3][4];
        #pragma unroll
        for (int a_ = 0; a_ < 3; ++a_) { acc[a_][0]=0; acc[a_][1]=0; acc[a_][2]=0; acc[a_][3]=0; }
        const int j0 = half * 384;
        for (int jt = 0; jt < 48; ++jt) {
            const int jb = j0 + jt * 8;
            float aa[3][8];
            #pragma unroll
            for (int hh = 0; hh < 3; ++hh) {
                *(float4*)&aa[hh][0] = *(float4*)&lg[(hset*3+hh)*LGS + jb];
                *(float4*)&aa[hh][4] = *(float4*)&lg[(hset*3+hh)*LGS + jb + 4];
            }
            #pragma unroll
            for (int u = 0; u < 8; ++u) {
                float4 zv = *(const float4*)(zb + (size_t)(jb + u) * CZn);
                #pragma unroll
                for (int hh = 0; hh < 3; ++hh) {
                    acc[hh][0] += aa[hh][u] * zv.x;
                    acc[hh][1] += aa[hh][u] * zv.y;
                    acc[hh][2] += aa[hh][u] * zv.z;
                    acc[hh][3] += aa[hh][u] * zv.w;
                }
            }
        }
        #pragma unroll
        for (int hh = 0; hh < 3; ++hh)
            #pragma unroll
            for (int cc = 0; cc < 4; ++cc)
                part[half][(hset*3+hh)*CZn + c4*4 + cc] = acc[hh][cc];
    }

    // ---------------- o (H*C=192) and o_pt (288) accumulators --------------
    {
        float acc1 = 0.f, acc2 = 0.f;
        const float* src1; int str1, h1;
        if (t < 192) { src1 = v + t;            str1 = 192; h1 = t >> 4; }
        else         { const int p = t - 192; src1 = v_pts + p; str1 = 288; h1 = p / 24; }
        const bool has2 = (t < 224);
        const int p2 = t + 64;
        const float* src2 = v_pts + p2;
        const int h2 = p2 / 24;
        for (int jt = 0; jt < 96; ++jt) {
            const int jb = jt * 8;
            float a1[8], a2[8];
            *(float4*)&a1[0] = *(float4*)&lg[h1*LGS + jb];
            *(float4*)&a1[4] = *(float4*)&lg[h1*LGS + jb + 4];
            if (has2) {
                *(float4*)&a2[0] = *(float4*)&lg[h2*LGS + jb];
                *(float4*)&a2[4] = *(float4*)&lg[h2*LGS + jb + 4];
            }
            #pragma unroll
            for (int u = 0; u < 8; ++u) {
                acc1 += a1[u] * src1[(size_t)(jb + u) * str1];
                if (has2) acc2 += a2[u] * src2[(size_t)(jb + u) * 288];
            }
        }
        float* catr = cat + (size_t)i * CONCATn;
        if (t < 192) catr[t] = acc1;
        else         ptsum[t - 192] = acc1;
        if (has2)    ptsum[t + 64] = acc2;
        __syncthreads();

        for (int x = t; x < Hn * CZn; x += 256)
            catr[576 + x] = part[0][x] + part[1][x];

        if (t < 96) {
            const float gx = ptsum[t*3+0] - trans[i*3+0];
            const float gy = ptsum[t*3+1] - trans[i*3+1];
            const float gz = ptsum[t*3+2] - trans[i*3+2];
            const float lx = rot[i*9+0]*gx + rot[i*9+3]*gy + rot[i*9+6]*gz;
            const float ly = rot[i*9+1]*gx + rot[i*9+4]*gy + rot[i*9+7]*gz;
            const float lz = rot[i*9+2]*gx + rot[i*9+5]*gy + rot[i*9+8]*gz;
            catr[192 + t] = lx;
            catr[288 + t] = ly;
            catr[384 + t] = lz;
            catr[480 + t] = sqrtf(lx*lx + ly*ly + lz*lz + 1e-8f);
        }
    }
}

// ---------------------------------------------------------------------------
// Kernel 3: out = cat @ Wout + bout.  Grid (192 row-tiles x 3 col-tiles),
// 128 threads: 4 rows x 32 float4-output-lanes, unroll 8 for MLP.
// ---------------------------------------------------------------------------
__global__ __launch_bounds__(128) void out_kernel(
    const float* __restrict__ cat, const float* __restrict__ Wout,
    const float* __restrict__ bout, float* __restrict__ out)
{
    const int rt = blockIdx.x;     // 0..191 : 4 rows each
    const int ot = blockIdx.y;     // 0..2   : 128 outputs each
    __shared__ float cl[4 * CONCATn];   // 33792 B
    const int r0 = rt * 4;
    const float4* cb = (const float4*)(cat + (size_t)r0 * CONCATn);
    for (int idx = threadIdx.x; idx < CONCATn; idx += 128)
        ((float4*)cl)[idx] = cb[idx];
    __syncthreads();

    const int t = threadIdx.x;
    const int r  = t >> 5;              // 0..3
    const int o4 = t & 31;              // 0..31
    const int col = ot * 128 + o4 * 4;
    float4 acc; acc.x = 0.f; acc.y = 0.f; acc.z = 0.f; acc.w = 0.f;
    const float* wp = Wout + col;
    const float* cr = cl + r * CONCATn;
    #pragma unroll 8
    for (int kk = 0; kk < CONCATn; ++kk) {
        float4 wv = *(const float4*)(wp + (size_t)kk * 384);
        float cv = cr[kk];
        acc.x += cv * wv.x; acc.y += cv * wv.y;
        acc.z += cv * wv.z; acc.w += cv * wv.w;
    }
    const float4 bo = *(const float4*)(bout + col);
    acc.x += bo.x; acc.y += bo.y; acc.z += bo.z; acc.w += bo.w;
    *(float4*)(out + (size_t)(r0 + r) * 384 + col) = acc;
}

// ---------------------------------------------------------------------------
extern "C" void kernel_launch(void* const* d_in, const int* in_sizes, int n_in,
                              void* d_out, int out_size, void* d_ws, size_t ws_size,
                              hipStream_t stream)
{
    const float* s     = (const float*)d_in[0];
    const float* z     = (const float*)d_in[1];
    const float* rot   = (const float*)d_in[2];
    const float* trans = (const float*)d_in[3];
    const float* mask  = (const float*)d_in[4];
    const float* Wq    = (const float*)d_in[5];
    const float* bq    = (const float*)d_in[6];
    const float* Wkv   = (const float*)d_in[7];
    const float* bkv   = (const float*)d_in[8];
    const float* Wqp   = (const float*)d_in[9];
    const float* bqp   = (const float*)d_in[10];
    const float* Wkvp  = (const float*)d_in[11];
    const float* bkvp  = (const float*)d_in[12];
    const float* Wb    = (const float*)d_in[13];
    const float* bb    = (const float*)d_in[14];
    const float* head_w= (const float*)d_in[15];
    const float* Wout  = (const float*)d_in[16];
    const float* bout  = (const float*)d_in[17];
    float* out = (float*)d_out;

    float* ws    = (float*)d_ws;
    float* q     = ws;                  // 768*192   = 147456
    float* kT    = q     + 147456;      // 147456  ([H*C][N])
    float* v     = kT    + 147456;      // 147456
    float* q_pts = v     + 147456;      // 110592
    float* kpT   = q_pts + 110592;      // 110592  ([H*PQ*3][N])
    float* v_pts = kpT   + 110592;      // 221184
    float* cat   = v_pts + 221184;      // 1622016

    hipLaunchKernelGGL(proj_kernel, dim3(96), dim3(256), 0, stream,
        s, rot, trans, Wq, bq, Wkv, bkv, Wqp, bqp, Wkvp, bkvp,
        q, kT, v, q_pts, kpT, v_pts);
    hipLaunchKernelGGL(row_kernel, dim3(NN), dim3(256), 0, stream,
        z, mask, rot, trans, q, kT, v, q_pts, kpT, v_pts, Wb, bb, head_w, cat);
    hipLaunchKernelGGL(out_kernel, dim3(192, 3), dim3(128), 0, stream,
        cat, Wout, bout, out);
}

// Round 4
// 772.606 us; speedup vs baseline: 1.1632x; 1.1632x over previous
//
#include <hip/hip_runtime.h>
#include <math.h>

#define NN 768
#define CSn 384
#define CZn 128
#define Cn 16
#define Hn 12
#define PQn 4
#define PVn 8
#define CONCATn 2112

// ---------------------------------------------------------------------------
// Kernel 1: input projections.  96 blocks x 8 rows each.
//   q      : [N][H*C]
//   kT     : [H*C][N]   (transposed for coalesced row_kernel reads)
//   v      : [N][H][C]
//   q_pts  : [N][H*PQ][3] (global frame)
//   kpT    : [H*PQ*3][N] (transposed, global frame)
//   v_pts  : [N][H][PV][3]
// ---------------------------------------------------------------------------
__global__ __launch_bounds__(256) void proj_kernel(
    const float* __restrict__ s, const float* __restrict__ rot, const float* __restrict__ trans,
    const float* __restrict__ Wq, const float* __restrict__ bq,
    const float* __restrict__ Wkv, const float* __restrict__ bkv,
    const float* __restrict__ Wqp, const float* __restrict__ bqp,
    const float* __restrict__ Wkvp, const float* __restrict__ bkvp,
    float* __restrict__ q, float* __restrict__ kT, float* __restrict__ v,
    float* __restrict__ q_pts, float* __restrict__ kpT, float* __restrict__ v_pts)
{
    const int rt = blockIdx.x;         // 0..95
    const int t  = threadIdx.x;
    const int r0 = rt * 8;
    __shared__ float sl[8][CSn];       // 12 KB
    __shared__ float lin[8][1152];     // 36.9 KB

    const float4* s4 = (const float4*)(s + (size_t)r0 * CSn);
    for (int idx = t; idx < 8 * CSn / 4; idx += 256)
        ((float4*)&sl[0][0])[idx] = s4[idx];
    __syncthreads();

    for (int slot = t; slot < 288; slot += 256) {
        const int col = slot * 4;
        const float* W; const float* bias; int cw; int fout;
        if (col < 192)      { W = Wq;   bias = bq;   cw = col;       fout = 192; }
        else if (col < 576) { W = Wkv;  bias = bkv;  cw = col - 192; fout = 384; }
        else if (col < 720) { W = Wqp;  bias = bqp;  cw = col - 576; fout = 144; }
        else                { W = Wkvp; bias = bkvp; cw = col - 720; fout = 432; }
        float4 bv = *(const float4*)(bias + cw);
        float4 acc[8];
        #pragma unroll
        for (int r = 0; r < 8; ++r) acc[r] = bv;
        const float* Wp = W + cw;
        #pragma unroll 8
        for (int kk = 0; kk < CSn; ++kk) {
            float4 w = *(const float4*)(Wp + (size_t)kk * fout);
            #pragma unroll
            for (int r = 0; r < 8; ++r) {
                float cv = sl[r][kk];
                acc[r].x += cv * w.x; acc[r].y += cv * w.y;
                acc[r].z += cv * w.z; acc[r].w += cv * w.w;
            }
        }
        #pragma unroll
        for (int r = 0; r < 8; ++r) *(float4*)&lin[r][col] = acc[r];
    }
    __syncthreads();

    for (int r = 0; r < 8; ++r) {
        const int i = r0 + r;
        if (t < 192) q[(size_t)i * 192 + t] = lin[r][t];
        for (int tt = t; tt < 384; tt += 256) {
            const int h = tt >> 5, cc = tt & 31;
            const float val = lin[r][192 + tt];
            if (cc < 16) kT[(size_t)(h * 16 + cc) * NN + i] = val;
            else         v[((size_t)i * Hn + h) * Cn + (cc - 16)] = val;
        }
        const float R0 = rot[i*9+0], R1 = rot[i*9+1], R2 = rot[i*9+2];
        const float R3 = rot[i*9+3], R4 = rot[i*9+4], R5 = rot[i*9+5];
        const float R6 = rot[i*9+6], R7 = rot[i*9+7], R8 = rot[i*9+8];
        const float T0 = trans[i*3+0], T1 = trans[i*3+1], T2 = trans[i*3+2];
        if (t < 48) {   // q points
            const float px = lin[r][576 + t], py = lin[r][576 + 48 + t], pz = lin[r][576 + 96 + t];
            const float gx = R0*px + R1*py + R2*pz + T0;
            const float gy = R3*px + R4*py + R5*pz + T1;
            const float gz = R6*px + R7*py + R8*pz + T2;
            float* qp = q_pts + ((size_t)i * 48 + t) * 3;
            qp[0] = gx; qp[1] = gy; qp[2] = gz;
        }
        if (t < 144) {  // kv points
            const float px = lin[r][720 + t], py = lin[r][720 + 144 + t], pz = lin[r][720 + 288 + t];
            const float gx = R0*px + R1*py + R2*pz + T0;
            const float gy = R3*px + R4*py + R5*pz + T1;
            const float gz = R6*px + R7*py + R8*pz + T2;
            const int h = t / 12, pp = t % 12;
            if (pp < 4) {
                float* dst = kpT + (size_t)(h * 12 + pp * 3) * NN + i;
                dst[0] = gx; dst[NN] = gy; dst[2*NN] = gz;
            } else {
                float* dst = v_pts + ((size_t)i * Hn + h) * PVn * 3 + (pp - 4) * 3;
                dst[0] = gx; dst[1] = gy; dst[2] = gz;
            }
        }
    }
}

// ---------------------------------------------------------------------------
// Kernel 2: per-row fused IPA.  One block per query row i.
// lg moved to GLOBAL workspace (lgG raw logits, aG softmax'd attention) so
// LDS = 13.4 KB -> high occupancy.  aG may alias lgG if ws is small.
// ---------------------------------------------------------------------------
__global__ __launch_bounds__(256) void row_kernel(
    const float* __restrict__ z, const float* __restrict__ mask,
    const float* __restrict__ rot, const float* __restrict__ trans,
    const float* __restrict__ q, const float* __restrict__ kT, const float* __restrict__ v,
    const float* __restrict__ q_pts, const float* __restrict__ kpT, const float* __restrict__ v_pts,
    const float* __restrict__ Wb, const float* __restrict__ bb, const float* __restrict__ head_w,
    float* __restrict__ lgG, float* __restrict__ aG, float* __restrict__ cat)
{
    const int i = blockIdx.x;
    const int t = threadIdx.x;
    __shared__ float part[2][Hn * CZn];   // 12288 B
    __shared__ float ptsum[Hn * PVn * 3]; // 1152 B

    const float S_QK = 0.14433756729740643f;   // sqrt(1/48)
    const float S_B  = 0.5773502691896258f;    // sqrt(1/3)
    const float S_PT = 0.1360827634879543f;    // sqrt(1/54)
    float coef[12];
    #pragma unroll
    for (int h = 0; h < 12; ++h) coef[h] = -0.5f * S_PT * log1pf(expf(head_w[h]));
    const float mi = mask[i];
    const int w = t >> 6, l = t & 63;

    float* lgi = lgG + (size_t)i * Hn * NN;
    const float* ai = aG + (size_t)i * Hn * NN;
    float* aiw = aG + (size_t)i * Hn * NN;

    // ---------------- Phase A: logits (z@Wb + qk + point attention) --------
    const float* qrow  = q     + (size_t)i * Hn * Cn;
    const float* qprow = q_pts + (size_t)i * Hn * PQn * 3;
    #pragma unroll 1
    for (int jj = 0; jj < 3; ++jj) {
        const int j = t + jj * 256;
        const float4* zr = (const float4*)(z + ((size_t)i * NN + j) * CZn);
        float bh[12];
        #pragma unroll
        for (int h = 0; h < 12; ++h) bh[h] = bb[h];
        #pragma unroll 4
        for (int c4 = 0; c4 < 32; ++c4) {
            float4 zv = zr[c4];
            #pragma unroll
            for (int h = 0; h < 12; ++h) {
                bh[h] += zv.x * Wb[(c4*4+0)*12 + h] + zv.y * Wb[(c4*4+1)*12 + h]
                       + zv.z * Wb[(c4*4+2)*12 + h] + zv.w * Wb[(c4*4+3)*12 + h];
            }
        }
        const float mterm = 100000.0f * (mi * mask[j] - 1.0f);
        #pragma unroll
        for (int h = 0; h < 12; ++h) {
            float qk = 0.f;
            const float* kc = kT + (size_t)(h * 16) * NN + j;
            #pragma unroll
            for (int c = 0; c < 16; ++c) qk += qrow[h * 16 + c] * kc[(size_t)c * NN];
            float d2s = 0.f;
            const float* kp = kpT + (size_t)(h * 12) * NN + j;
            #pragma unroll
            for (int e = 0; e < 12; ++e) { float d = qprow[h * 12 + e] - kp[(size_t)e * NN]; d2s += d * d; }
            lgi[h * NN + j] = S_QK * qk + S_B * bh[h] + coef[h] * d2s + mterm;
        }
    }
    __syncthreads();   // drains stores (vmcnt 0) -> lgi visible block-wide via L2

    // ---------------- Phase B: softmax over j (wave w owns 3 heads) --------
    {
        for (int hh = 0; hh < 3; ++hh) {
            const int h = w * 3 + hh;
            float e[12];
            #pragma unroll
            for (int u = 0; u < 12; ++u) e[u] = lgi[h * NN + l + u * 64];
            float m = -1e30f;
            #pragma unroll
            for (int u = 0; u < 12; ++u) m = fmaxf(m, e[u]);
            #pragma unroll
            for (int off = 32; off > 0; off >>= 1) m = fmaxf(m, __shfl_xor(m, off));
            float ssum = 0.f;
            #pragma unroll
            for (int u = 0; u < 12; ++u) { e[u] = expf(e[u] - m); ssum += e[u]; }
            #pragma unroll
            for (int off = 32; off > 0; off >>= 1) ssum += __shfl_xor(ssum, off);
            const float inv = 1.0f / ssum;
            #pragma unroll
            for (int u = 0; u < 12; ++u) aiw[h * NN + l + u * 64] = e[u] * inv;
        }
    }
    __syncthreads();

    // ---------------- Phase C: o_pair = a . z  (z row from L2/L3) ----------
    {
        const int half = t >> 7, tt = t & 127;
        const int hset = tt >> 5, c4 = tt & 31;
        const float* zb = z + (size_t)i * NN * CZn + c4 * 4;
        float acc[3][4];
        #pragma unroll
        for (int a_ = 0; a_ < 3; ++a_) { acc[a_][0]=0; acc[a_][1]=0; acc[a_][2]=0; acc[a_][3]=0; }
        const int j0 = half * 384;
        for (int jt = 0; jt < 48; ++jt) {
            const int jb = j0 + jt * 8;
            float aa[3][8];
            #pragma unroll
            for (int hh = 0; hh < 3; ++hh) {
                *(float4*)&aa[hh][0] = *(const float4*)(ai + (hset*3+hh)*NN + jb);
                *(float4*)&aa[hh][4] = *(const float4*)(ai + (hset*3+hh)*NN + jb + 4);
            }
            #pragma unroll
            for (int u = 0; u < 8; ++u) {
                float4 zv = *(const float4*)(zb + (size_t)(jb + u) * CZn);
                #pragma unroll
                for (int hh = 0; hh < 3; ++hh) {
                    acc[hh][0] += aa[hh][u] * zv.x;
                    acc[hh][1] += aa[hh][u] * zv.y;
                    acc[hh][2] += aa[hh][u] * zv.z;
                    acc[hh][3] += aa[hh][u] * zv.w;
                }
            }
        }
        #pragma unroll
        for (int hh = 0; hh < 3; ++hh)
            #pragma unroll
            for (int cc = 0; cc < 4; ++cc)
                part[half][(hset*3+hh)*CZn + c4*4 + cc] = acc[hh][cc];
    }

    // ---------------- o (H*C=192) and o_pt (288) accumulators --------------
    {
        float acc1 = 0.f, acc2 = 0.f;
        const float* src1; int str1, h1;
        if (t < 192) { src1 = v + t;            str1 = 192; h1 = t >> 4; }
        else         { const int p = t - 192; src1 = v_pts + p; str1 = 288; h1 = p / 24; }
        const bool has2 = (t < 224);
        const int p2 = t + 64;
        const float* src2 = v_pts + p2;
        const int h2 = p2 / 24;
        for (int jt = 0; jt < 96; ++jt) {
            const int jb = jt * 8;
            float a1[8], a2[8];
            *(float4*)&a1[0] = *(const float4*)(ai + h1*NN + jb);
            *(float4*)&a1[4] = *(const float4*)(ai + h1*NN + jb + 4);
            if (has2) {
                *(float4*)&a2[0] = *(const float4*)(ai + h2*NN + jb);
                *(float4*)&a2[4] = *(const float4*)(ai + h2*NN + jb + 4);
            }
            #pragma unroll
            for (int u = 0; u < 8; ++u) {
                acc1 += a1[u] * src1[(size_t)(jb + u) * str1];
                if (has2) acc2 += a2[u] * src2[(size_t)(jb + u) * 288];
            }
        }
        float* catr = cat + (size_t)i * CONCATn;
        if (t < 192) catr[t] = acc1;
        else         ptsum[t - 192] = acc1;
        if (has2)    ptsum[t + 64] = acc2;
        __syncthreads();

        for (int x = t; x < Hn * CZn; x += 256)
            catr[576 + x] = part[0][x] + part[1][x];

        if (t < 96) {
            const float gx = ptsum[t*3+0] - trans[i*3+0];
            const float gy = ptsum[t*3+1] - trans[i*3+1];
            const float gz = ptsum[t*3+2] - trans[i*3+2];
            const float lx = rot[i*9+0]*gx + rot[i*9+3]*gy + rot[i*9+6]*gz;
            const float ly = rot[i*9+1]*gx + rot[i*9+4]*gy + rot[i*9+7]*gz;
            const float lz = rot[i*9+2]*gx + rot[i*9+5]*gy + rot[i*9+8]*gz;
            catr[192 + t] = lx;
            catr[288 + t] = ly;
            catr[384 + t] = lz;
            catr[480 + t] = sqrtf(lx*lx + ly*ly + lz*lz + 1e-8f);
        }
    }
}

// ---------------------------------------------------------------------------
// Kernel 3: out = cat @ Wout + bout.  Grid (192 row-tiles x 3 col-tiles),
// 128 threads: 4 rows x 32 float4-output-lanes.
// ---------------------------------------------------------------------------
__global__ __launch_bounds__(128) void out_kernel(
    const float* __restrict__ cat, const float* __restrict__ Wout,
    const float* __restrict__ bout, float* __restrict__ out)
{
    const int rt = blockIdx.x;     // 0..191
    const int ot = blockIdx.y;     // 0..2
    __shared__ float cl[4 * CONCATn];   // 33792 B
    const int r0 = rt * 4;
    const float4* cb = (const float4*)(cat + (size_t)r0 * CONCATn);
    for (int idx = threadIdx.x; idx < CONCATn; idx += 128)
        ((float4*)cl)[idx] = cb[idx];
    __syncthreads();

    const int t = threadIdx.x;
    const int r  = t >> 5;
    const int o4 = t & 31;
    const int col = ot * 128 + o4 * 4;
    float4 acc; acc.x = 0.f; acc.y = 0.f; acc.z = 0.f; acc.w = 0.f;
    const float* wp = Wout + col;
    const float* cr = cl + r * CONCATn;
    #pragma unroll 8
    for (int kk = 0; kk < CONCATn; ++kk) {
        float4 wv = *(const float4*)(wp + (size_t)kk * 384);
        float cv = cr[kk];
        acc.x += cv * wv.x; acc.y += cv * wv.y;
        acc.z += cv * wv.z; acc.w += cv * wv.w;
    }
    const float4 bo = *(const float4*)(bout + col);
    acc.x += bo.x; acc.y += bo.y; acc.z += bo.z; acc.w += bo.w;
    *(float4*)(out + (size_t)(r0 + r) * 384 + col) = acc;
}

// ---------------------------------------------------------------------------
extern "C" void kernel_launch(void* const* d_in, const int* in_sizes, int n_in,
                              void* d_out, int out_size, void* d_ws, size_t ws_size,
                              hipStream_t stream)
{
    const float* s     = (const float*)d_in[0];
    const float* z     = (const float*)d_in[1];
    const float* rot   = (const float*)d_in[2];
    const float* trans = (const float*)d_in[3];
    const float* mask  = (const float*)d_in[4];
    const float* Wq    = (const float*)d_in[5];
    const float* bq    = (const float*)d_in[6];
    const float* Wkv   = (const float*)d_in[7];
    const float* bkv   = (const float*)d_in[8];
    const float* Wqp   = (const float*)d_in[9];
    const float* bqp   = (const float*)d_in[10];
    const float* Wkvp  = (const float*)d_in[11];
    const float* bkvp  = (const float*)d_in[12];
    const float* Wb    = (const float*)d_in[13];
    const float* bb    = (const float*)d_in[14];
    const float* head_w= (const float*)d_in[15];
    const float* Wout  = (const float*)d_in[16];
    const float* bout  = (const float*)d_in[17];
    float* out = (float*)d_out;

    float* ws    = (float*)d_ws;
    float* q     = ws;                  // 147456
    float* kT    = q     + 147456;      // 147456
    float* v     = kT    + 147456;      // 147456
    float* q_pts = v     + 147456;      // 110592
    float* kpT   = q_pts + 110592;      // 110592
    float* v_pts = kpT   + 110592;      // 221184
    float* cat   = v_pts + 221184;      // 1622016
    float* lgG   = cat   + 1622016;     // 7077888  (27 MB)
    // aG: separate buffer if workspace allows (avoids in-place global RMW
    // across the barrier); else alias lgG.
    const size_t need_dbuf = (size_t)(2506752 + 2 * 7077888) * 4;
    float* aG = (ws_size >= need_dbuf) ? (lgG + 7077888) : lgG;

    hipLaunchKernelGGL(proj_kernel, dim3(96), dim3(256), 0, stream,
        s, rot, trans, Wq, bq, Wkv, bkv, Wqp, bqp, Wkvp, bkvp,
        q, kT, v, q_pts, kpT, v_pts);
    hipLaunchKernelGGL(row_kernel, dim3(NN), dim3(256), 0, stream,
        z, mask, rot, trans, q, kT, v, q_pts, kpT, v_pts, Wb, bb, head_w,
        lgG, aG, cat);
    hipLaunchKernelGGL(out_kernel, dim3(192, 3), dim3(128), 0, stream,
        cat, Wout, bout, out);
}

// Round 5
// 579.179 us; speedup vs baseline: 1.5516x; 1.3340x over previous
//
#include <hip/hip_runtime.h>
#include <math.h>

#define NN 768
#define CSn 384
#define CZn 128
#define Hn 12
#define CONCATn 2112

// ---------------------------------------------------------------------------
// K1: linG[768][1152] = s @ [Wq|Wkv|Wqp|Wkvp] + bias.  Grid (48 rt, 18 ct).
// ---------------------------------------------------------------------------
__global__ __launch_bounds__(256, 4) void proj_gemm(
    const float* __restrict__ s,
    const float* __restrict__ Wq, const float* __restrict__ bq,
    const float* __restrict__ Wkv, const float* __restrict__ bkv,
    const float* __restrict__ Wqp, const float* __restrict__ bqp,
    const float* __restrict__ Wkvp, const float* __restrict__ bkvp,
    float* __restrict__ linG)
{
    const int rt = blockIdx.x;      // 16-row tile
    const int ct = blockIdx.y;      // 64-col tile
    const int t = threadIdx.x;
    const int r0 = rt * 16;
    __shared__ float sl[16 * 388];  // stride 388: bank-decorrelated, 16B-aligned rows
    for (int x4 = t; x4 < 1536; x4 += 256) {
        const int r = x4 / 96, c4 = x4 % 96;
        *(float4*)&sl[r * 388 + c4 * 4] = *(const float4*)(s + (size_t)(r0 + r) * CSn + c4 * 4);
    }
    __syncthreads();
    const int c = t & 63, rq = t >> 6;
    const int col = ct * 64 + c;
    const float* Wp; int fout; float bias;
    if (col < 192)      { Wp = Wq + col;         fout = 192; bias = bq[col]; }
    else if (col < 576) { Wp = Wkv + (col-192);  fout = 384; bias = bkv[col-192]; }
    else if (col < 720) { Wp = Wqp + (col-576);  fout = 144; bias = bqp[col-576]; }
    else                { Wp = Wkvp + (col-720); fout = 432; bias = bkvp[col-720]; }
    float a0=bias, a1=bias, a2=bias, a3=bias;
    const float* s0 = sl + (rq*4+0)*388;
    const float* s1 = sl + (rq*4+1)*388;
    const float* s2 = sl + (rq*4+2)*388;
    const float* s3 = sl + (rq*4+3)*388;
    #pragma unroll 4
    for (int kk = 0; kk < 384; ++kk) {
        const float wv = *Wp; Wp += fout;
        a0 += s0[kk]*wv; a1 += s1[kk]*wv; a2 += s2[kk]*wv; a3 += s3[kk]*wv;
    }
    float* lr = linG + (size_t)(r0 + rq*4) * 1152 + col;
    lr[0] = a0; lr[1152] = a1; lr[2*1152] = a2; lr[3*1152] = a3;
}

// ---------------------------------------------------------------------------
// K2: scatter linG -> q,k,v (row-major [N][192]), q_pts/kp ([N][144]),
//     v_pts ([N][288]); block 0 also builds WbT[12][128].
// ---------------------------------------------------------------------------
__global__ __launch_bounds__(256) void scatter_kernel(
    const float* __restrict__ linG, const float* __restrict__ rot, const float* __restrict__ trans,
    const float* __restrict__ Wb,
    float* __restrict__ q, float* __restrict__ k, float* __restrict__ v,
    float* __restrict__ qp, float* __restrict__ kp, float* __restrict__ vp,
    float* __restrict__ WbT)
{
    const int i = blockIdx.x, t = threadIdx.x;
    const float* lr = linG + (size_t)i * 1152;
    if (t < 192) q[(size_t)i*192 + t] = lr[t];
    for (int tt = t; tt < 384; tt += 256) {
        const int h = tt >> 5, cc = tt & 31;
        const float val = lr[192 + tt];
        if (cc < 16) k[(size_t)i*192 + h*16 + cc] = val;
        else         v[(size_t)i*192 + h*16 + (cc-16)] = val;
    }
    const float R0 = rot[i*9+0], R1 = rot[i*9+1], R2 = rot[i*9+2];
    const float R3 = rot[i*9+3], R4 = rot[i*9+4], R5 = rot[i*9+5];
    const float R6 = rot[i*9+6], R7 = rot[i*9+7], R8 = rot[i*9+8];
    const float T0 = trans[i*3+0], T1 = trans[i*3+1], T2 = trans[i*3+2];
    if (t < 48) {
        const float px = lr[576 + t], py = lr[576 + 48 + t], pz = lr[576 + 96 + t];
        float* d = qp + (size_t)i*144 + t*3;
        d[0] = R0*px + R1*py + R2*pz + T0;
        d[1] = R3*px + R4*py + R5*pz + T1;
        d[2] = R6*px + R7*py + R8*pz + T2;
    }
    if (t < 144) {
        const float px = lr[720 + t], py = lr[720 + 144 + t], pz = lr[720 + 288 + t];
        const float gx = R0*px + R1*py + R2*pz + T0;
        const float gy = R3*px + R4*py + R5*pz + T1;
        const float gz = R6*px + R7*py + R8*pz + T2;
        const int h = t / 12, pp = t % 12;
        float* d = (pp < 4) ? (kp + (size_t)i*144 + h*12 + pp*3)
                            : (vp + (size_t)i*288 + ((h*8) + (pp-4))*3);
        d[0] = gx; d[1] = gy; d[2] = gz;
    }
    if (i == 0) for (int x = t; x < 1536; x += 256) WbT[x] = Wb[(x & 127)*12 + (x >> 7)];
}

// ---------------------------------------------------------------------------
// K3: logits.  Grid (12 jt, 768 i) = 9216 blocks.  64 j per block; each j
// owned by a 4-lane quad: lanes split 128 z-channels in interleaved 16B
// chunks (2x line amplification vs 8x), shuffle-reduce bh, then lane g
// finishes heads 3g..3g+2 (qk + point-att) and writes lgG.
// ---------------------------------------------------------------------------
__global__ __launch_bounds__(256, 8) void logits_kernel(
    const float* __restrict__ z, const float* __restrict__ mask,
    const float* __restrict__ q, const float* __restrict__ k,
    const float* __restrict__ qp, const float* __restrict__ kp,
    const float* __restrict__ WbT, const float* __restrict__ bb, const float* __restrict__ head_w,
    float* __restrict__ lgG)
{
    const int jt = blockIdx.x, i = blockIdx.y, t = threadIdx.x;
    __shared__ float qs[192], qps[144], coefS[12];
    if (t < 192) qs[t] = q[(size_t)i*192 + t];
    if (t < 144) qps[t] = qp[(size_t)i*144 + t];
    if (t < 12) coefS[t] = -0.5f * 0.1360827634879543f * log1pf(expf(head_w[t]));
    __syncthreads();

    const int jl = t >> 2, g = t & 3;
    const int j = jt * 64 + jl;
    const float* zr = z + ((size_t)i * NN + j) * CZn + g * 4;
    float bh[12];
    #pragma unroll
    for (int h = 0; h < 12; ++h) bh[h] = 0.f;
    #pragma unroll
    for (int u = 0; u < 8; ++u) {
        const float4 zv = *(const float4*)(zr + u * 16);
        const float* wb = WbT + u*16 + g*4;
        #pragma unroll
        for (int h = 0; h < 12; ++h) {
            const float4 wv = *(const float4*)(wb + h * 128);
            bh[h] += zv.x*wv.x + zv.y*wv.y + zv.z*wv.z + zv.w*wv.w;
        }
    }
    #pragma unroll
    for (int h = 0; h < 12; ++h) {
        bh[h] += __shfl_xor(bh[h], 1);
        bh[h] += __shfl_xor(bh[h], 2);
    }
    // lane g takes heads 3g..3g+2 (static selects; no runtime reg indexing)
    float bsel[3];
    #pragma unroll
    for (int hh = 0; hh < 3; ++hh) {
        const float v01 = (g & 1) ? bh[3+hh] : bh[0+hh];
        const float v23 = (g & 1) ? bh[9+hh] : bh[6+hh];
        bsel[hh] = (g & 2) ? v23 : v01;
    }
    const float mterm = 100000.0f * (mask[i] * mask[j] - 1.0f);
    const float* kr  = k  + (size_t)j * 192;
    const float* kpr = kp + (size_t)j * 144;
    float* lgr = lgG + (size_t)i * (Hn*NN) + j;
    #pragma unroll
    for (int hh = 0; hh < 3; ++hh) {
        const int h = 3*g + hh;
        float qk = 0.f;
        #pragma unroll
        for (int c4 = 0; c4 < 4; ++c4) {
            const float4 kv = *(const float4*)(kr + h*16 + c4*4);
            const float4 qv = *(const float4*)(qs + h*16 + c4*4);
            qk += kv.x*qv.x + kv.y*qv.y + kv.z*qv.z + kv.w*qv.w;
        }
        float d2s = 0.f;
        #pragma unroll
        for (int e4 = 0; e4 < 3; ++e4) {
            const float4 kpv = *(const float4*)(kpr + h*12 + e4*4);
            const float4 qpv = *(const float4*)(qps + h*12 + e4*4);
            const float d0 = qpv.x-kpv.x, d1 = qpv.y-kpv.y;
            const float d2 = qpv.z-kpv.z, d3 = qpv.w-kpv.w;
            d2s += d0*d0 + d1*d1 + d2*d2 + d3*d3;
        }
        lgr[h * NN] = 0.14433756729740643f*qk + 0.5773502691896258f*(bsel[hh] + bb[h])
                    + coefS[h]*d2s + mterm;
    }
}

// ---------------------------------------------------------------------------
// K4: softmax over j.  Grid 768; wave w owns 3 heads.  In-place safe.
// ---------------------------------------------------------------------------
__global__ __launch_bounds__(256, 8) void softmax_kernel(
    const float* __restrict__ lgG, float* __restrict__ aG)
{
    const int i = blockIdx.x, t = threadIdx.x;
    const int w = t >> 6, l = t & 63;
    const float* lgi = lgG + (size_t)i * Hn*NN;
    float* aiw = aG + (size_t)i * Hn*NN;
    for (int hh = 0; hh < 3; ++hh) {
        const int h = w*3 + hh;
        float e[12];
        #pragma unroll
        for (int u = 0; u < 12; ++u) e[u] = lgi[h*NN + l + u*64];
        float m = -1e30f;
        #pragma unroll
        for (int u = 0; u < 12; ++u) m = fmaxf(m, e[u]);
        #pragma unroll
        for (int off = 32; off > 0; off >>= 1) m = fmaxf(m, __shfl_xor(m, off));
        float ssum = 0.f;
        #pragma unroll
        for (int u = 0; u < 12; ++u) { e[u] = expf(e[u] - m); ssum += e[u]; }
        #pragma unroll
        for (int off = 32; off > 0; off >>= 1) ssum += __shfl_xor(ssum, off);
        const float inv = 1.0f / ssum;
        #pragma unroll
        for (int u = 0; u < 12; ++u) aiw[h*NN + l + u*64] = e[u] * inv;
    }
}

// ---------------------------------------------------------------------------
// K5: o (192) + o_pt (288) + frame-invert + norms.  Grid (768 i, 2 half).
// half*240+t -> output index (o<192: plain o; else o_pt channel p=o-192).
// ---------------------------------------------------------------------------
__global__ __launch_bounds__(256, 8) void opt_kernel(
    const float* __restrict__ aG, const float* __restrict__ v, const float* __restrict__ vp,
    const float* __restrict__ rot, const float* __restrict__ trans,
    float* __restrict__ cat)
{
    const int i = blockIdx.x, half = blockIdx.y, t = threadIdx.x;
    __shared__ float pts[240];
    if (t < 240) {
        const int o = half*240 + t;
        float acc = 0.f;
        if (o < 192) {
            const float* ar = aG + ((size_t)i*Hn + (o >> 4))*NN;
            const float* src = v + o;
            for (int jb = 0; jb < NN; jb += 8) {
                const float4 A0 = *(const float4*)(ar + jb);
                const float4 A1 = *(const float4*)(ar + jb + 4);
                acc += A0.x*src[(size_t)(jb+0)*192] + A0.y*src[(size_t)(jb+1)*192]
                     + A0.z*src[(size_t)(jb+2)*192] + A0.w*src[(size_t)(jb+3)*192]
                     + A1.x*src[(size_t)(jb+4)*192] + A1.y*src[(size_t)(jb+5)*192]
                     + A1.z*src[(size_t)(jb+6)*192] + A1.w*src[(size_t)(jb+7)*192];
            }
            cat[(size_t)i*CONCATn + o] = acc;
        } else {
            const int p = o - 192;
            const float* ar = aG + ((size_t)i*Hn + (p / 24))*NN;
            const float* src = vp + p;
            for (int jb = 0; jb < NN; jb += 8) {
                const float4 A0 = *(const float4*)(ar + jb);
                const float4 A1 = *(const float4*)(ar + jb + 4);
                acc += A0.x*src[(size_t)(jb+0)*288] + A0.y*src[(size_t)(jb+1)*288]
                     + A0.z*src[(size_t)(jb+2)*288] + A0.w*src[(size_t)(jb+3)*288]
                     + A1.x*src[(size_t)(jb+4)*288] + A1.y*src[(size_t)(jb+5)*288]
                     + A1.z*src[(size_t)(jb+6)*288] + A1.w*src[(size_t)(jb+7)*288];
            }
            pts[half ? t : (t - 192)] = acc;
        }
    }
    __syncthreads();
    const int ntrip = half ? 80 : 16;
    const int hbase = half ? 16 : 0;
    if (t < ntrip) {
        const float gx = pts[t*3+0] - trans[i*3+0];
        const float gy = pts[t*3+1] - trans[i*3+1];
        const float gz = pts[t*3+2] - trans[i*3+2];
        const float lx = rot[i*9+0]*gx + rot[i*9+3]*gy + rot[i*9+6]*gz;
        const float ly = rot[i*9+1]*gx + rot[i*9+4]*gy + rot[i*9+7]*gz;
        const float lz = rot[i*9+2]*gx + rot[i*9+5]*gy + rot[i*9+8]*gz;
        const int hpv = hbase + t;
        float* catr = cat + (size_t)i*CONCATn;
        catr[192 + hpv] = lx;
        catr[288 + hpv] = ly;
        catr[384 + hpv] = lz;
        catr[480 + hpv] = sqrtf(lx*lx + ly*ly + lz*lz + 1e-8f);
    }
}

// ---------------------------------------------------------------------------
// K6: o_pair = a . z.  Grid (768 i, 2 c-half); thread = (c, head-group of 3).
// a loads are wave-uniform (readfirstlane) -> scalar; z loads coalesced.
// ---------------------------------------------------------------------------
__global__ __launch_bounds__(256, 8) void opair_kernel(
    const float* __restrict__ aG, const float* __restrict__ z, float* __restrict__ cat)
{
    const int i = blockIdx.x, half = blockIdx.y, t = threadIdx.x;
    const int c = half*64 + (t & 63);
    const int hg = __builtin_amdgcn_readfirstlane(t >> 6);
    const float* a0 = aG + ((size_t)i*Hn + hg*3)*NN;
    const float* a1 = a0 + NN;
    const float* a2 = a1 + NN;
    const float* zc = z + (size_t)i*NN*CZn + c;
    float x0=0.f, x1=0.f, x2=0.f;
    #pragma unroll 2
    for (int j = 0; j < NN; j += 4) {
        const float4 A0 = *(const float4*)(a0 + j);
        const float4 A1 = *(const float4*)(a1 + j);
        const float4 A2 = *(const float4*)(a2 + j);
        const float z0 = zc[(size_t)(j+0)*CZn];
        const float z1 = zc[(size_t)(j+1)*CZn];
        const float z2 = zc[(size_t)(j+2)*CZn];
        const float z3 = zc[(size_t)(j+3)*CZn];
        x0 += A0.x*z0 + A0.y*z1 + A0.z*z2 + A0.w*z3;
        x1 += A1.x*z0 + A1.y*z1 + A1.z*z2 + A1.w*z3;
        x2 += A2.x*z0 + A2.y*z1 + A2.z*z2 + A2.w*z3;
    }
    float* cr = cat + (size_t)i*CONCATn + 576 + c;
    cr[(size_t)(hg*3+0)*CZn] = x0;
    cr[(size_t)(hg*3+1)*CZn] = x1;
    cr[(size_t)(hg*3+2)*CZn] = x2;
}

// ---------------------------------------------------------------------------
// K7: out = cat @ Wout + bout.  Grid (192, 3), 128 thr.
// ---------------------------------------------------------------------------
__global__ __launch_bounds__(128) void out_kernel(
    const float* __restrict__ cat, const float* __restrict__ Wout,
    const float* __restrict__ bout, float* __restrict__ out)
{
    const int rt = blockIdx.x;
    const int ot = blockIdx.y;
    __shared__ float cl[4 * CONCATn];
    const int r0 = rt * 4;
    const float4* cb = (const float4*)(cat + (size_t)r0 * CONCATn);
    for (int idx = threadIdx.x; idx < CONCATn; idx += 128)
        ((float4*)cl)[idx] = cb[idx];
    __syncthreads();
    const int t = threadIdx.x;
    const int r  = t >> 5;
    const int o4 = t & 31;
    const int col = ot * 128 + o4 * 4;
    float4 acc; acc.x = 0.f; acc.y = 0.f; acc.z = 0.f; acc.w = 0.f;
    const float* wp = Wout + col;
    const float* cr = cl + r * CONCATn;
    #pragma unroll 8
    for (int kk = 0; kk < CONCATn; ++kk) {
        const float4 wv = *(const float4*)(wp + (size_t)kk * 384);
        const float cv = cr[kk];
        acc.x += cv * wv.x; acc.y += cv * wv.y;
        acc.z += cv * wv.z; acc.w += cv * wv.w;
    }
    const float4 bo = *(const float4*)(bout + col);
    acc.x += bo.x; acc.y += bo.y; acc.z += bo.z; acc.w += bo.w;
    *(float4*)(out + (size_t)(r0 + r) * 384 + col) = acc;
}

// ---------------------------------------------------------------------------
extern "C" void kernel_launch(void* const* d_in, const int* in_sizes, int n_in,
                              void* d_out, int out_size, void* d_ws, size_t ws_size,
                              hipStream_t stream)
{
    const float* s     = (const float*)d_in[0];
    const float* z     = (const float*)d_in[1];
    const float* rot   = (const float*)d_in[2];
    const float* trans = (const float*)d_in[3];
    const float* mask  = (const float*)d_in[4];
    const float* Wq    = (const float*)d_in[5];
    const float* bq    = (const float*)d_in[6];
    const float* Wkv   = (const float*)d_in[7];
    const float* bkv   = (const float*)d_in[8];
    const float* Wqp   = (const float*)d_in[9];
    const float* bqp   = (const float*)d_in[10];
    const float* Wkvp  = (const float*)d_in[11];
    const float* bkvp  = (const float*)d_in[12];
    const float* Wb    = (const float*)d_in[13];
    const float* bb    = (const float*)d_in[14];
    const float* head_w= (const float*)d_in[15];
    const float* Wout  = (const float*)d_in[16];
    const float* bout  = (const float*)d_in[17];
    float* out = (float*)d_out;

    float* ws    = (float*)d_ws;
    float* q     = ws;                  // 147456
    float* k     = q     + 147456;      // 147456  [N][192]
    float* v     = k     + 147456;      // 147456  [N][192]
    float* qp    = v     + 147456;      // 110592  [N][144]
    float* kp    = qp    + 110592;      // 110592  [N][144]
    float* vp    = kp    + 110592;      // 221184  [N][288]
    float* WbT   = vp    + 221184;      // 1536    [12][128]
    float* cat   = WbT   + 1536;        // 1622016
    float* lgG   = cat   + 1622016;     // 7077888 (also linG during proj)
    float* linG  = lgG;                 // overlay: dead before logits runs
    const size_t need_dbuf = (size_t)(9586176 + 2ull*7077888 - 7077888 + 7077888) * 4; // 66.6 MB
    float* aG = (ws_size >= (size_t)16664064 * 4) ? (lgG + 7077888) : lgG;
    (void)need_dbuf;

    hipLaunchKernelGGL(proj_gemm, dim3(48, 18), dim3(256), 0, stream,
        s, Wq, bq, Wkv, bkv, Wqp, bqp, Wkvp, bkvp, linG);
    hipLaunchKernelGGL(scatter_kernel, dim3(768), dim3(256), 0, stream,
        linG, rot, trans, Wb, q, k, v, qp, kp, vp, WbT);
    hipLaunchKernelGGL(logits_kernel, dim3(12, 768), dim3(256), 0, stream,
        z, mask, q, k, qp, kp, WbT, bb, head_w, lgG);
    hipLaunchKernelGGL(softmax_kernel, dim3(768), dim3(256), 0, stream,
        lgG, aG);
    hipLaunchKernelGGL(opt_kernel, dim3(768, 2), dim3(256), 0, stream,
        aG, v, vp, rot, trans, cat);
    hipLaunchKernelGGL(opair_kernel, dim3(768, 2), dim3(256), 0, stream,
        aG, z, cat);
    hipLaunchKernelGGL(out_kernel, dim3(192, 3), dim3(128), 0, stream,
        cat, Wout, bout, out);
}